// Round 12
// baseline (604.556 us; speedup 1.0000x reference)
//
#include <hip/hip_runtime.h>
#include <hip/hip_bf16.h>
#include <cstdint>

// Shapes: B=512, S=196, I=2048, Q=1024, H=512
// ques_attn == ques_feat exactly (softmax over singleton axis). Only img_attn computed:
//   cc[b][h]  = sum_q qf[b][q]*w2g[q][h] + b2g[h] + b2x[h]
//   score[r]  = sum_h tanh( sum_k X[r][k]*w2x[k][h] + cc[b(r)][h] ) * w2h[h]   (r = b*196+s)
//   a = softmax_s(score);  img_attn[b][f] = sum_s a[b][s] * X[b][s][f]
//
// r12: H-SPLIT scores GEMM. score's h-sum is additive -> grid 3136 = (1568 M-tiles
// x 2 col-halves), partials in sc0/sc1 summed by softmax (no atomics). Block =
// 256 threads (4 waves), wave owns 64 of the half's 256 cols; acc 64 AGPR.
// launch_bounds(256,2) -> 2 waves/SIMD -> 256-reg cap: B TRIPLE-buffered (96 VGPR,
// loaded 2 steps ahead -> L2 latency fully hidden; transitive vmcnt force hits only
// DMA issued >=2 steps prior >= HBM latency). LDS 4x16KB -> 2 blocks/CU overlap.
// Grid pair-swizzle: halves of a tile are 8 blockIdx apart -> same XCD -> the
// second X read L2-hits (X loads no longer NT for this reason).

typedef __attribute__((ext_vector_type(8))) short bf16x8;
typedef __attribute__((ext_vector_type(4))) float f32x4;

typedef __attribute__((address_space(1))) const unsigned int as1_uint;
typedef __attribute__((address_space(3))) unsigned int as3_uint;

__device__ inline unsigned short f2bf(float f) {
    union { float f; unsigned u; } v; v.f = f;
    unsigned u = v.u;
    u += 0x7FFFu + ((u >> 16) & 1u);
    return (unsigned short)(u >> 16);
}

__device__ inline unsigned pk2(float lo, float hi) {
    __hip_bfloat162 h = __float22bfloat162_rn(make_float2(lo, hi));
    return *reinterpret_cast<unsigned*>(&h);
}

__device__ inline unsigned pkq(unsigned a, unsigned b) {
    union { unsigned u; float f; } x, y; x.u = a; y.u = b;
    return pk2(x.f, y.f);
}

// 8 f32 (two uint4) -> bf16x8 via v_cvt_pk_bf16_f32
__device__ inline bf16x8 cvt8(uint4 lo, uint4 hi) {
    union { unsigned u[4]; bf16x8 v; } r;
    r.u[0] = pkq(lo.x, lo.y); r.u[1] = pkq(lo.z, lo.w);
    r.u[2] = pkq(hi.x, hi.y); r.u[3] = pkq(hi.z, hi.w);
    return r.v;
}

// ---------------- out0 = ques_feat (exact copy) ----------------
__global__ void k_copy(const float* __restrict__ src, float* __restrict__ dst) {
    int i = blockIdx.x * blockDim.x + threadIdx.x;
    reinterpret_cast<float4*>(dst)[i] = reinterpret_cast<const float4*>(src)[i];
}

// ---------------- WTf: fragment-major packed bf16 of w2x^T ----------------
// Tile (kblk, nblk) = 64 k x 16 cols: [kc8 0..7][col 0..15][j 0..7];
// a wave's B-fragment read (16 cols x 32 k) is one contiguous 1 KB access.
__global__ void k_pack_w(const float* __restrict__ w, unsigned short* __restrict__ wtf) {
    int kblk = blockIdx.x >> 5;
    int nblk = blockIdx.x & 31;
    int t = threadIdx.x;          // 128: (kc8, col)
    int kc8 = t >> 4, col = t & 15;
    const float* src = w + (size_t)(kblk * 64 + kc8 * 8) * 512 + nblk * 16 + col;
    unsigned short* dst = wtf + (size_t)(kblk * 32 + nblk) * 1024 + kc8 * 128 + col * 8;
    unsigned short tmp[8];
    #pragma unroll
    for (int j = 0; j < 8; ++j) tmp[j] = f2bf(src[(size_t)j * 512]);
    *reinterpret_cast<uint4*>(dst) = *reinterpret_cast<const uint4*>(tmp);
}

// ---------------- cc[b][h] = qf[b]·w2g[:,h] + b2g[h] + b2x[h] ----------------
__global__ void k_cconst(const float* __restrict__ qf, const float* __restrict__ w2g,
                         const float* __restrict__ b2g, const float* __restrict__ b2x,
                         float* __restrict__ cc) {
    __shared__ float qls[2][1024];
    int b0 = blockIdx.x * 2;
    int t = threadIdx.x;
    #pragma unroll
    for (int j = 0; j < 2; ++j) {
        int idx = j * 256 + t;
        int bb = idx >> 8, c4 = idx & 255;
        float4 v = reinterpret_cast<const float4*>(qf + (size_t)(b0 + bb) * 1024)[c4];
        qls[bb][c4 * 4 + 0] = v.x; qls[bb][c4 * 4 + 1] = v.y;
        qls[bb][c4 * 4 + 2] = v.z; qls[bb][c4 * 4 + 3] = v.w;
    }
    __syncthreads();
    float a00 = 0.f, a01 = 0.f, a10 = 0.f, a11 = 0.f;
    #pragma unroll 8
    for (int q = 0; q < 1024; ++q) {
        float w0 = w2g[q * 512 + t];
        float w1 = w2g[q * 512 + 256 + t];
        float q0 = qls[0][q], q1 = qls[1][q];
        a00 += q0 * w0; a01 += q0 * w1;
        a10 += q1 * w0; a11 += q1 * w1;
    }
    float c0 = b2g[t] + b2x[t];
    float c1 = b2g[t + 256] + b2x[t + 256];
    cc[(size_t)b0 * 512 + t] = a00 + c0;
    cc[(size_t)b0 * 512 + t + 256] = a01 + c1;
    cc[(size_t)(b0 + 1) * 512 + t] = a10 + c0;
    cc[(size_t)(b0 + 1) * 512 + t + 256] = a11 + c1;
}

// ---------------- scores (half): fused GEMM + tanh + partial dot(w2h) ----------------
// LDS image: granule (16B = 4 f32) at pos p = row*16 + pc holds source col-group
// gcol = pc ^ (row&15) (involution). DMA dest linear; per-lane swizzled SOURCE.
// A-frag read: ds_read_b128 at pc = (kh*8 + l4*2 + h) ^ l15 -> conflict-free.
#define NSTEP 32

__global__ __launch_bounds__(256, 2) void k_scores(
    const float* __restrict__ X, const unsigned short* __restrict__ WTf,
    const float* __restrict__ cc, const float* __restrict__ w2h,
    float* __restrict__ sc0, float* __restrict__ sc1)
{
    __shared__ __align__(16) char Ab[4][16384];   // 4 x 16KB f32 A-buffers
    __shared__ float slds[64];

    int tid = threadIdx.x;
    int wave = tid >> 6, lane = tid & 63;
    int l15 = lane & 15, l4 = lane >> 4;

    // pair swizzle: halves of one tile are 8 blockIdx apart -> same XCD (i%8)
    int bi = blockIdx.x;
    int tile = (bi >> 4) * 8 + (bi & 7);
    int half = (bi >> 3) & 1;
    int r0 = tile * 64;

    // staging: 4 granules/thread/step (rows sr+16j, j=0..3)
    int sr = tid >> 4;            // 0..15
    int spc = tid & 15;
    int gswz = (spc ^ sr) << 4;   // swizzled source byte offset in 256B step-chunk
    const char* xs0 = reinterpret_cast<const char*>(X + (size_t)(r0 + sr) * 2048) + gswz;
    const char* xs1 = reinterpret_cast<const char*>(X + (size_t)(r0 + 16 + sr) * 2048) + gswz;
    const char* xs2 = reinterpret_cast<const char*>(X + (size_t)(r0 + 32 + sr) * 2048) + gswz;
    const char* xs3 = reinterpret_cast<const char*>(X + (size_t)(r0 + 48 + sr) * 2048) + gswz;
    char* ldsw = &Ab[0][0] + wave * 1024;   // + bufofs + j*4096 (lane*16 implicit)

    // B fragment base for this half: nblk = half*16 + wave*4 + n
    const unsigned short* wb0 = WTf + (size_t)(half * 16 + wave * 4) * 1024
                                + l4 * 128 + l15 * 8;

    // A fragment byte voffsets
    const char* abase = &Ab[0][0];
    int off00 = l15 * 256 + (((l4 * 2 + 0) ^ l15) << 4);
    int off01 = l15 * 256 + (((l4 * 2 + 1) ^ l15) << 4);
    int off10 = l15 * 256 + (((8 + l4 * 2 + 0) ^ l15) << 4);
    int off11 = l15 * 256 + (((8 + l4 * 2 + 1) ^ l15) << 4);

    if (tid < 64) slds[tid] = 0.0f;

    f32x4 acc[4][4];
    #pragma unroll
    for (int m = 0; m < 4; ++m)
        #pragma unroll
        for (int n = 0; n < 4; ++n) acc[m][n] = (f32x4){0.f, 0.f, 0.f, 0.f};

    // B triple-buffer: set s holds steps t%3==s; [0..3]=kh0 n0..3, [4..7]=kh1
    bf16x8 b0[8], b1[8], b2[8];

    #define GLL(src, dst) __builtin_amdgcn_global_load_lds( \
        (as1_uint*)(src), (as3_uint*)(dst), 16, 0, 0)

    #define GLOAD4(bufofs, step) do { \
        GLL(xs0 + (size_t)(step) * 256, ldsw + (bufofs)); \
        GLL(xs1 + (size_t)(step) * 256, ldsw + (bufofs) + 4096); \
        GLL(xs2 + (size_t)(step) * 256, ldsw + (bufofs) + 8192); \
        GLL(xs3 + (size_t)(step) * 256, ldsw + (bufofs) + 12288); } while (0)

    #define BLOAD8(dst, t) do { \
        const unsigned short* bp = wb0 + (size_t)(t) * 32768; \
        dst[0] = *reinterpret_cast<const bf16x8*>(bp); \
        dst[1] = *reinterpret_cast<const bf16x8*>(bp + 1024); \
        dst[2] = *reinterpret_cast<const bf16x8*>(bp + 2048); \
        dst[3] = *reinterpret_cast<const bf16x8*>(bp + 3072); \
        dst[4] = *reinterpret_cast<const bf16x8*>(bp + 512); \
        dst[5] = *reinterpret_cast<const bf16x8*>(bp + 1536); \
        dst[6] = *reinterpret_cast<const bf16x8*>(bp + 2560); \
        dst[7] = *reinterpret_cast<const bf16x8*>(bp + 3584); } while (0)

    #define MF(brp, bufofs, offL, offH) do { \
        __builtin_amdgcn_s_setprio(1); \
        _Pragma("unroll") \
        for (int m = 0; m < 4; ++m) { \
            uint4 lo = *reinterpret_cast<const uint4*>(abase + (bufofs) + m * 4096 + (offL)); \
            uint4 hi = *reinterpret_cast<const uint4*>(abase + (bufofs) + m * 4096 + (offH)); \
            bf16x8 af = cvt8(lo, hi); \
            _Pragma("unroll") \
            for (int n = 0; n < 4; ++n) \
                acc[m][n] = __builtin_amdgcn_mfma_f32_16x16x32_bf16(af, (brp)[n], acc[m][n], 0, 0, 0); \
        } \
        __builtin_amdgcn_s_setprio(0); } while (0)

    #define SBAR __builtin_amdgcn_sched_barrier(0)

    // STEP(T, CUR, NXT): consume set CUR (loaded 2 steps ago), load NXT for T+2,
    // issue DMA(T+3) FIRST so B(T+2)'s later wait transitively forces only
    // DMA(T+1) (issued >=2 steps earlier).
    #define STEP(T, CUR, NXT) do { \
        const int bo_ = ((T) & 3) * 16384; \
        if ((T) + 3 < NSTEP) GLOAD4((((T) + 3) & 3) * 16384, (T) + 3); \
        if ((T) + 2 < NSTEP) BLOAD8(NXT, (T) + 2); \
        SBAR; \
        MF((CUR), bo_, off00, off01); \
        MF((CUR) + 4, bo_, off10, off11); \
        SBAR; \
        __builtin_amdgcn_s_barrier(); } while (0)

    // prologue: DMA 0..2; B sets for steps 0,1; retire DMA(0) only
    GLOAD4(0, 0);
    GLOAD4(16384, 1);
    GLOAD4(32768, 2);
    BLOAD8(b0, 0);
    BLOAD8(b1, 1);
    asm volatile("s_waitcnt vmcnt(24)" ::: "memory");   // 12 DMA + 16 B - 4 oldest
    __builtin_amdgcn_s_barrier();

    #pragma unroll 1
    for (int T = 0; T < 30; T += 3) {
        STEP(T,     b0, b2);
        STEP(T + 1, b1, b0);
        STEP(T + 2, b2, b1);
    }
    STEP(30, b0, b2);
    STEP(31, b1, b0);

    // fence: keep epilogue constant loads out of the K-loop
    asm volatile("" ::: "memory");

    // epilogue: partial score over this half's 256 cols
    int b0r = r0 / 196;
    int sbreak = (b0r + 1) * 196 - r0;
    int b1r = b0r + 1; if (b1r > 511) b1r = 511;
    float cch0[4], cch1[4], whv[4];
    #pragma unroll
    for (int n = 0; n < 4; ++n) {
        int h = half * 256 + wave * 64 + n * 16 + l15;
        cch0[n] = cc[(size_t)b0r * 512 + h];
        cch1[n] = cc[(size_t)b1r * 512 + h];
        whv[n] = w2h[h];
    }
    #pragma unroll
    for (int m = 0; m < 4; ++m) {
        #pragma unroll
        for (int i = 0; i < 4; ++i) {
            int row = m * 16 + l4 * 4 + i;
            float p = 0.0f;
            #pragma unroll
            for (int n = 0; n < 4; ++n) {
                float x = acc[m][n][i] + ((row < sbreak) ? cch0[n] : cch1[n]);
                float th = 1.0f - 2.0f / (__expf(2.0f * x) + 1.0f);
                p += th * whv[n];
            }
            p += __shfl_xor(p, 1);
            p += __shfl_xor(p, 2);
            p += __shfl_xor(p, 4);
            p += __shfl_xor(p, 8);
            if (l15 == 0) atomicAdd(&slds[row], p);
        }
    }
    __syncthreads();
    if (tid < 64) {
        float* dst = half ? sc1 : sc0;
        dst[(size_t)r0 + tid] = slds[tid];
    }
}

// ---------------- softmax over s (196) per b, summing the two half-partials ----------------
__global__ void k_softmax(const float* __restrict__ sc0, const float* __restrict__ sc1,
                          float* __restrict__ a) {
    int b = blockIdx.x, t = threadIdx.x;
    __shared__ float red[8];
    float v = -3.0e38f;
    if (t < 196) v = sc0[(size_t)b * 196 + t] + sc1[(size_t)b * 196 + t];
    float m = v;
    for (int o = 32; o > 0; o >>= 1) m = fmaxf(m, __shfl_xor(m, o));
    if ((t & 63) == 0) red[t >> 6] = m;
    __syncthreads();
    m = fmaxf(fmaxf(red[0], red[1]), fmaxf(red[2], red[3]));
    float e = (t < 196) ? __expf(v - m) : 0.0f;
    float s = e;
    for (int o = 32; o > 0; o >>= 1) s += __shfl_xor(s, o);
    if ((t & 63) == 0) red[4 + (t >> 6)] = s;
    __syncthreads();
    float tot = red[4] + red[5] + red[6] + red[7];
    if (t < 196) a[(size_t)b * 196 + t] = e / tot;
}

// ---------------- img_attn[b][f] = sum_s a[b][s] * X[b][s][f] ----------------
__global__ void k_wsum(const float* __restrict__ X, const float* __restrict__ a,
                       float* __restrict__ out1) {
    __shared__ float als[196];
    int b = blockIdx.x >> 1;
    int fh = (blockIdx.x & 1) * 1024;
    int t = threadIdx.x;
    if (t < 196) als[t] = a[(size_t)b * 196 + t];
    __syncthreads();
    int f = fh + t * 4;
    const float* Xb = X + (size_t)b * 196 * 2048 + f;
    float4 acc = {0.f, 0.f, 0.f, 0.f};
    #pragma unroll 4
    for (int s = 0; s < 196; ++s) {
        float4 x = *reinterpret_cast<const float4*>(Xb + (size_t)s * 2048);
        float w = als[s];
        acc.x += w * x.x; acc.y += w * x.y; acc.z += w * x.z; acc.w += w * x.w;
    }
    *reinterpret_cast<float4*>(out1 + (size_t)b * 2048 + f) = acc;
}

extern "C" void kernel_launch(void* const* d_in, const int* in_sizes, int n_in,
                              void* d_out, int out_size, void* d_ws, size_t ws_size,
                              hipStream_t stream) {
    const float* qf  = (const float*)d_in[0];
    const float* X   = (const float*)d_in[1];
    const float* w2x = (const float*)d_in[6];
    const float* b2x = (const float*)d_in[7];
    const float* w2g = (const float*)d_in[8];
    const float* b2g = (const float*)d_in[9];
    const float* w2h = (const float*)d_in[10];

    float* out0 = (float*)d_out;                 // ques_attn = ques_feat (512x1024)
    float* out1 = out0 + 512 * 1024;             // img_attn (512x2048)

    // ws: [0,2MB) WTf; [2MB,3MB) cc; [3MB,3.5MB) sc0; [3.5MB,4MB) sc1; [4MB,4.5MB) a
    unsigned short* WTf = (unsigned short*)d_ws;
    float* cc  = (float*)((char*)d_ws + (size_t)(2u << 20));
    float* sc0 = (float*)((char*)d_ws + (size_t)(3u << 20));
    float* sc1 = (float*)((char*)d_ws + (size_t)(3u << 20) + (512u << 10));
    float* aw  = (float*)((char*)d_ws + (size_t)(4u << 20));

    k_copy<<<512, 256, 0, stream>>>(qf, out0);
    k_pack_w<<<1024, 128, 0, stream>>>(w2x, WTf);
    k_cconst<<<256, 256, 0, stream>>>(qf, w2g, b2g, b2x, cc);
    k_scores<<<3136, 256, 0, stream>>>(X, WTf, cc, w2h, sc0, sc1);
    k_softmax<<<512, 256, 0, stream>>>(sc0, sc1, aw);
    k_wsum<<<1024, 256, 0, stream>>>(X, aw, out1);
}

// Round 13
// 523.230 us; speedup vs baseline: 1.1554x; 1.1554x over previous
//
#include <hip/hip_runtime.h>
#include <hip/hip_bf16.h>
#include <cstdint>

// Shapes: B=512, S=196, I=2048, Q=1024, H=512
// ques_attn == ques_feat exactly (softmax over singleton axis). Only img_attn computed:
//   cc[b][h]  = sum_q qf[b][q]*w2g[q][h] + b2g[h] + b2x[h]
//   score[r]  = sum_h tanh( sum_k X[r][k]*w2x[k][h] + cc[b(r)][h] ) * w2h[h]   (r = b*196+s)
//   a = softmax_s(score);  img_attn[b][f] = sum_s a[b][s] * X[b][s][f]
//
// r13 = r9 k_scores (best: f32-X direct DMA staging, 4x16KB LDS, 2 blocks/CU,
// distance-3 DMA, NT) + consolidation: out0 copy fused into k_cconst (free: same
// float4s it already loads), softmax fused into k_wsum. 6 kernels -> 4.

typedef __attribute__((ext_vector_type(8))) short bf16x8;
typedef __attribute__((ext_vector_type(4))) float f32x4;

typedef __attribute__((address_space(1))) const unsigned int as1_uint;
typedef __attribute__((address_space(3))) unsigned int as3_uint;

__device__ inline unsigned short f2bf(float f) {
    union { float f; unsigned u; } v; v.f = f;
    unsigned u = v.u;
    u += 0x7FFFu + ((u >> 16) & 1u);
    return (unsigned short)(u >> 16);
}

__device__ inline unsigned pk2(float lo, float hi) {
    __hip_bfloat162 h = __float22bfloat162_rn(make_float2(lo, hi));
    return *reinterpret_cast<unsigned*>(&h);
}

__device__ inline unsigned pkq(unsigned a, unsigned b) {
    union { unsigned u; float f; } x, y; x.u = a; y.u = b;
    return pk2(x.f, y.f);
}

// 8 f32 (two uint4) -> bf16x8 via v_cvt_pk_bf16_f32
__device__ inline bf16x8 cvt8(uint4 lo, uint4 hi) {
    union { unsigned u[4]; bf16x8 v; } r;
    r.u[0] = pkq(lo.x, lo.y); r.u[1] = pkq(lo.z, lo.w);
    r.u[2] = pkq(hi.x, hi.y); r.u[3] = pkq(hi.z, hi.w);
    return r.v;
}

// ---------------- WTf: fragment-major packed bf16 of w2x^T ----------------
// Tile (kblk, nblk) = 64 k x 16 cols: [kc8 0..7][col 0..15][j 0..7];
// a wave's B-fragment read (16 cols x 32 k) is one contiguous 1 KB access.
__global__ void k_pack_w(const float* __restrict__ w, unsigned short* __restrict__ wtf) {
    int kblk = blockIdx.x >> 5;
    int nblk = blockIdx.x & 31;
    int t = threadIdx.x;          // 128: (kc8, col)
    int kc8 = t >> 4, col = t & 15;
    const float* src = w + (size_t)(kblk * 64 + kc8 * 8) * 512 + nblk * 16 + col;
    unsigned short* dst = wtf + (size_t)(kblk * 32 + nblk) * 1024 + kc8 * 128 + col * 8;
    unsigned short tmp[8];
    #pragma unroll
    for (int j = 0; j < 8; ++j) tmp[j] = f2bf(src[(size_t)j * 512]);
    *reinterpret_cast<uint4*>(dst) = *reinterpret_cast<const uint4*>(tmp);
}

// ---------------- cc[b][h] = qf[b]·w2g[:,h] + b2g[h] + b2x[h]  (+ out0 copy) ----------------
// The qf float4s staged into LDS are also the out0 payload -> copy is free.
__global__ void k_cconst(const float* __restrict__ qf, const float* __restrict__ w2g,
                         const float* __restrict__ b2g, const float* __restrict__ b2x,
                         float* __restrict__ cc, float* __restrict__ out0) {
    __shared__ float qls[2][1024];
    int b0 = blockIdx.x * 2;
    int t = threadIdx.x;
    #pragma unroll
    for (int j = 0; j < 2; ++j) {
        int idx = j * 256 + t;
        int bb = idx >> 8, c4 = idx & 255;
        float4 v = reinterpret_cast<const float4*>(qf + (size_t)(b0 + bb) * 1024)[c4];
        qls[bb][c4 * 4 + 0] = v.x; qls[bb][c4 * 4 + 1] = v.y;
        qls[bb][c4 * 4 + 2] = v.z; qls[bb][c4 * 4 + 3] = v.w;
        reinterpret_cast<float4*>(out0 + (size_t)(b0 + bb) * 1024)[c4] = v;   // out0 = qf
    }
    __syncthreads();
    float a00 = 0.f, a01 = 0.f, a10 = 0.f, a11 = 0.f;
    #pragma unroll 8
    for (int q = 0; q < 1024; ++q) {
        float w0 = w2g[q * 512 + t];
        float w1 = w2g[q * 512 + 256 + t];
        float q0 = qls[0][q], q1 = qls[1][q];
        a00 += q0 * w0; a01 += q0 * w1;
        a10 += q1 * w0; a11 += q1 * w1;
    }
    float c0 = b2g[t] + b2x[t];
    float c1 = b2g[t + 256] + b2x[t + 256];
    cc[(size_t)b0 * 512 + t] = a00 + c0;
    cc[(size_t)b0 * 512 + t + 256] = a01 + c1;
    cc[(size_t)(b0 + 1) * 512 + t] = a10 + c0;
    cc[(size_t)(b0 + 1) * 512 + t + 256] = a11 + c1;
}

// ---------------- scores: fused GEMM + tanh + dot(w2h), f32-X direct (r9) ----------------
// grid 1568 M-tiles of 64 rows; block 512 = 8 waves, wave owns 64 cols (acc 64 AGPR).
// K-step 64. A staged as f32: per step 64 rows x 64 f32 = 16KB = 1024 granules(16B).
// Granule at LDS pos p (=row*16+pc): content f32 col-group gcol = pc ^ (row&15)
// (involution) -> DMA dest linear (wave-uniform+lane*16), per-lane swizzled SOURCE.
// Frag read: two ds_read_b128 at pc=(kh*8+l4*2+h)^l15 -> conflict-free.
#define NSTEP 32

__global__ __launch_bounds__(512, 4) void k_scores(
    const float* __restrict__ X, const unsigned short* __restrict__ WTf,
    const float* __restrict__ cc, const float* __restrict__ w2h,
    float* __restrict__ scores)
{
    __shared__ __align__(16) char Ab[4][16384];   // 4 x 16KB f32 A-buffers
    __shared__ float slds[64];

    int tid = threadIdx.x;
    int wave = tid >> 6, lane = tid & 63;
    int l15 = lane & 15, l4 = lane >> 4;
    int r0 = blockIdx.x * 64;

    // staging: thread t stages granules t (rows 0..31) and t+512 (rows 32..63)
    int srow = tid >> 4, spc = tid & 15;
    const char* xsrc = reinterpret_cast<const char*>(X + (size_t)(r0 + srow) * 2048)
                       + ((spc ^ (srow & 15)) << 4);
    const char* xsrc2 = xsrc + (size_t)32 * 8192;   // row+32: same (row&15) -> same swizzle
    char* ldsw = &Ab[0][0] + wave * 1024;           // + bufofs (+8192 for 2nd granule)

    // B fragment base; (n,kh) offsets are immediates off bp
    const unsigned short* wb0 = WTf + (size_t)wave * 4096 + l4 * 128 + l15 * 8;

    // A fragment byte voffsets: l15*256 + (( kh*8 + l4*2 + h ) ^ l15)*16
    const char* abase = &Ab[0][0];
    int off00 = l15 * 256 + (((l4 * 2 + 0) ^ l15) << 4);
    int off01 = l15 * 256 + (((l4 * 2 + 1) ^ l15) << 4);
    int off10 = l15 * 256 + (((8 + l4 * 2 + 0) ^ l15) << 4);
    int off11 = l15 * 256 + (((8 + l4 * 2 + 1) ^ l15) << 4);

    if (tid < 64) slds[tid] = 0.0f;

    f32x4 acc[4][4];
    #pragma unroll
    for (int m = 0; m < 4; ++m)
        #pragma unroll
        for (int n = 0; n < 4; ++n) acc[m][n] = (f32x4){0.f, 0.f, 0.f, 0.f};

    bf16x8 brA[4], brB[4];

    // aux=2 (NT): X is a pure stream; don't evict the L2-hot WTf panel
    #define GLOAD2(bufofs, step) do { \
        __builtin_amdgcn_global_load_lds((as1_uint*)(xsrc + (step) * 256), \
            (as3_uint*)(ldsw + (bufofs)), 16, 0, 2); \
        __builtin_amdgcn_global_load_lds((as1_uint*)(xsrc2 + (step) * 256), \
            (as3_uint*)(ldsw + (bufofs) + 8192), 16, 0, 2); } while (0)

    #define BLOAD(dst, t, kh) do { \
        const unsigned short* bp = wb0 + (size_t)(t) * 32768 + (kh) * 512; \
        dst[0] = *reinterpret_cast<const bf16x8*>(bp); \
        dst[1] = *reinterpret_cast<const bf16x8*>(bp + 1024); \
        dst[2] = *reinterpret_cast<const bf16x8*>(bp + 2048); \
        dst[3] = *reinterpret_cast<const bf16x8*>(bp + 3072); } while (0)

    #define MF(br, bufofs, offL, offH) do { \
        __builtin_amdgcn_s_setprio(1); \
        _Pragma("unroll") \
        for (int m = 0; m < 4; ++m) { \
            uint4 lo = *reinterpret_cast<const uint4*>(abase + (bufofs) + m * 4096 + (offL)); \
            uint4 hi = *reinterpret_cast<const uint4*>(abase + (bufofs) + m * 4096 + (offH)); \
            bf16x8 af = cvt8(lo, hi); \
            _Pragma("unroll") \
            for (int n = 0; n < 4; ++n) \
                acc[m][n] = __builtin_amdgcn_mfma_f32_16x16x32_bf16(af, br[n], acc[m][n], 0, 0, 0); \
        } \
        __builtin_amdgcn_s_setprio(0); } while (0)

    #define SBAR __builtin_amdgcn_sched_barrier(0)

    // prologue: fill DMA pipeline 3 deep; brA's compiler wait (in-order vmcnt)
    // transitively retires DMA(0) before the first read.
    GLOAD2(0, 0);
    GLOAD2(16384, 1);
    GLOAD2(32768, 2);
    BLOAD(brA, 0, 0);
    asm volatile("s_waitcnt vmcnt(8)" ::: "memory");
    __builtin_amdgcn_s_barrier();

    // steady state: wait-for-brB(t-1) at step t-1 transitively retires DMA(t)
    // (issued step t-3, older) before barrier(t-1) -> buf t safe at step t.
    #pragma unroll 1
    for (int t = 0; t < NSTEP; ++t) {
        int bufofs = (t & 3) * 16384;
        BLOAD(brB, t, 1);
        MF(brA, bufofs, off00, off01);
        if (t + 1 < NSTEP) BLOAD(brA, t + 1, 0);
        MF(brB, bufofs, off10, off11);
        SBAR;
        if (t + 3 < NSTEP) GLOAD2(((t + 3) & 3) * 16384, t + 3);
        SBAR;
        __builtin_amdgcn_s_barrier();
    }

    // fence: keep epilogue constant loads out of the K-loop
    asm volatile("" ::: "memory");

    // epilogue: score[row] = sum_h tanh(feat + cc[b(row)][h]) * w2h[h]
    int b0 = r0 / 196;
    int sbreak = (b0 + 1) * 196 - r0;
    int b1 = b0 + 1; if (b1 > 511) b1 = 511;
    float cch0[4], cch1[4], whv[4];
    #pragma unroll
    for (int n = 0; n < 4; ++n) {
        int h = wave * 64 + n * 16 + l15;
        cch0[n] = cc[(size_t)b0 * 512 + h];
        cch1[n] = cc[(size_t)b1 * 512 + h];
        whv[n] = w2h[h];
    }
    #pragma unroll
    for (int m = 0; m < 4; ++m) {
        #pragma unroll
        for (int i = 0; i < 4; ++i) {
            int row = m * 16 + l4 * 4 + i;
            float p = 0.0f;
            #pragma unroll
            for (int n = 0; n < 4; ++n) {
                float x = acc[m][n][i] + ((row < sbreak) ? cch0[n] : cch1[n]);
                float th = 1.0f - 2.0f / (__expf(2.0f * x) + 1.0f);
                p += th * whv[n];
            }
            p += __shfl_xor(p, 1);
            p += __shfl_xor(p, 2);
            p += __shfl_xor(p, 4);
            p += __shfl_xor(p, 8);
            if (l15 == 0) atomicAdd(&slds[row], p);
        }
    }
    __syncthreads();
    if (tid < 64) scores[(size_t)r0 + tid] = slds[tid];
}

// ---------------- wsum with fused softmax ----------------
// grid 1024 = (b, col-half); each block recomputes its row's softmax (cheap:
// 196 loads + shuffle reduce) then does the 802KB weighted sum.
__global__ __launch_bounds__(256) void k_wsum_sm(const float* __restrict__ X,
                                                 const float* __restrict__ sc,
                                                 float* __restrict__ out1) {
    __shared__ float als[196];
    __shared__ float red[8];
    int b = blockIdx.x >> 1;
    int fh = (blockIdx.x & 1) * 1024;
    int t = threadIdx.x;

    // softmax over sc[b][0..195]
    float v = (t < 196) ? sc[(size_t)b * 196 + t] : -3.0e38f;
    float m = v;
    for (int o = 32; o > 0; o >>= 1) m = fmaxf(m, __shfl_xor(m, o));
    if ((t & 63) == 0) red[t >> 6] = m;
    __syncthreads();
    m = fmaxf(fmaxf(red[0], red[1]), fmaxf(red[2], red[3]));
    float e = (t < 196) ? __expf(v - m) : 0.0f;
    float s = e;
    for (int o = 32; o > 0; o >>= 1) s += __shfl_xor(s, o);
    if ((t & 63) == 0) red[4 + (t >> 6)] = s;
    __syncthreads();
    float tot = red[4] + red[5] + red[6] + red[7];
    if (t < 196) als[t] = e / tot;
    __syncthreads();

    // weighted sum over this half's 1024 cols
    int f = fh + t * 4;
    const float* Xb = X + (size_t)b * 196 * 2048 + f;
    float4 acc = {0.f, 0.f, 0.f, 0.f};
    #pragma unroll 4
    for (int ss = 0; ss < 196; ++ss) {
        float4 x = *reinterpret_cast<const float4*>(Xb + (size_t)ss * 2048);
        float w = als[ss];
        acc.x += w * x.x; acc.y += w * x.y; acc.z += w * x.z; acc.w += w * x.w;
    }
    *reinterpret_cast<float4*>(out1 + (size_t)b * 2048 + f) = acc;
}

extern "C" void kernel_launch(void* const* d_in, const int* in_sizes, int n_in,
                              void* d_out, int out_size, void* d_ws, size_t ws_size,
                              hipStream_t stream) {
    const float* qf  = (const float*)d_in[0];
    const float* X   = (const float*)d_in[1];
    const float* w2x = (const float*)d_in[6];
    const float* b2x = (const float*)d_in[7];
    const float* w2g = (const float*)d_in[8];
    const float* b2g = (const float*)d_in[9];
    const float* w2h = (const float*)d_in[10];

    float* out0 = (float*)d_out;                 // ques_attn = ques_feat (512x1024)
    float* out1 = out0 + 512 * 1024;             // img_attn (512x2048)

    // ws layout: [0,2MB) WTf bf16 packed; [2MB,3MB) cc f32; [3MB,..) scores f32 flat [100352]
    unsigned short* WTf = (unsigned short*)d_ws;
    float* cc = (float*)((char*)d_ws + (size_t)(2u << 20));
    float* sc = (float*)((char*)d_ws + (size_t)(3u << 20));

    k_pack_w<<<1024, 128, 0, stream>>>(w2x, WTf);
    k_cconst<<<256, 256, 0, stream>>>(qf, w2g, b2g, b2x, cc, out0);
    k_scores<<<1568, 512, 0, stream>>>(X, WTf, cc, w2h, sc);
    k_wsum_sm<<<1024, 256, 0, stream>>>(X, sc, out1);
}